// Round 2
// baseline (202.280 us; speedup 1.0000x reference)
//
#include <hip/hip_runtime.h>

#define NOBJ   32
#define DIM    128
#define HW     256
#define R1     8192
#define NPAIR  262144
#define BN_EPS 1e-5f

typedef unsigned short u16;
typedef __attribute__((ext_vector_type(8))) short bf16x8;
typedef __attribute__((ext_vector_type(4))) float f32x4;
typedef __attribute__((ext_vector_type(4))) unsigned short u16x4;

__device__ __forceinline__ u16 f2bf(float f) {
    union { float f; unsigned u; } v; v.f = f;
    unsigned r = v.u + 0x7fffu + ((v.u >> 16) & 1u);
    return (u16)(r >> 16);
}

__device__ __forceinline__ u16x4 cvt4(float4 v) {
    u16x4 r;
    r[0] = f2bf(v.x); r[1] = f2bf(v.y); r[2] = f2bf(v.z); r[3] = f2bf(v.w);
    return r;
}

// ---------------------------------------------------------------------------
// One-shot fp32 -> bf16 conversion of state + all weights.
// W1b gets the remapped layout [512][128]: row n<256 = w1[n][0:128] (source
// half), row n>=256 = w1[n-256][128:256] (target half).
// ---------------------------------------------------------------------------
__global__ __launch_bounds__(256) void convert_kernel(
    const float4* __restrict__ state, const float* __restrict__ w1,
    const float4* __restrict__ w2, const float4* __restrict__ fw1,
    const float4* __restrict__ fw2,
    u16x4* __restrict__ Ab, u16x4* __restrict__ W1b, u16x4* __restrict__ W2b,
    u16x4* __restrict__ FW1b, u16x4* __restrict__ FW2b)
{
    int g = blockIdx.x * 256 + threadIdx.x;
    if (g < 262144) { Ab[g] = cvt4(state[g]); return; }
    g -= 262144;
    if (g < 16384) {
        const int o = g * 4, n = o >> 7, k = o & 127;
        const float4 v = *(const float4*)(w1 + (n < 256 ? n * 256 + k
                                                        : (n - 256) * 256 + 128 + k));
        W1b[g] = cvt4(v); return;
    }
    g -= 16384;
    if (g < 8192) { W2b[g] = cvt4(w2[g]); return; }
    g -= 8192;
    if (g < 16384) { FW1b[g] = cvt4(fw1[g]); return; }
    g -= 16384;
    if (g < 8192) { FW2b[g] = cvt4(fw2[g]); }
}

// ---------------------------------------------------------------------------
// bf16 MFMA GEMM, direct global->register (operands are L2-resident).
// C[m,n] = sum_k A[m,k] * W[n,k] + bias_scale*bias[n]
// Wave tile 16*RF rows x 64 cols; 4 waves stacked -> BM = RF*64, BN = 64.
// For k >= KSPLIT the A-source switches to A2 (k-index rebased) — used to
// compute [state|agg] @ fw1^T without materializing the concat.
// ---------------------------------------------------------------------------
template<int RF, int K, int KSPLIT, bool BF16_OUT>
__global__ __launch_bounds__(256) void mfma_gemm(
    const u16* __restrict__ A, int lda,
    const u16* __restrict__ A2, int lda2,
    const u16* __restrict__ W,
    const float* __restrict__ bias, float bias_scale,
    void* __restrict__ Cout, int ldc)
{
    const int lane = threadIdx.x & 63;
    const int wave = threadIdx.x >> 6;
    const int row0 = blockIdx.y * (RF * 64) + wave * (RF * 16);
    const int col0 = blockIdx.x * 64;
    const int lr = lane & 15;
    const int lk = (lane >> 4) * 8;

    f32x4 acc[RF][4] = {};

    #pragma unroll
    for (int k0 = 0; k0 < K; k0 += 32) {
        const u16* Abase; int la;
        if (k0 < KSPLIT) { Abase = A + k0; la = lda; }
        else             { Abase = A2 + (k0 - KSPLIT); la = lda2; }
        bf16x8 afr[RF];
        #pragma unroll
        for (int rf = 0; rf < RF; ++rf)
            afr[rf] = *(const bf16x8*)(Abase + (size_t)(row0 + rf * 16 + lr) * la + lk);
        bf16x8 bfr[4];
        #pragma unroll
        for (int cf = 0; cf < 4; ++cf)
            bfr[cf] = *(const bf16x8*)(W + (size_t)(col0 + cf * 16 + lr) * K + k0 + lk);
        #pragma unroll
        for (int rf = 0; rf < RF; ++rf)
            #pragma unroll
            for (int cf = 0; cf < 4; ++cf)
                acc[rf][cf] = __builtin_amdgcn_mfma_f32_16x16x32_bf16(
                    afr[rf], bfr[cf], acc[rf][cf], 0, 0, 0);
    }

    #pragma unroll
    for (int rf = 0; rf < RF; ++rf) {
        #pragma unroll
        for (int cf = 0; cf < 4; ++cf) {
            const int col = col0 + cf * 16 + lr;
            const float bv = bias ? bias_scale * bias[col] : 0.f;
            #pragma unroll
            for (int r = 0; r < 4; ++r) {
                const int row = row0 + rf * 16 + (lane >> 4) * 4 + r;
                const float v = acc[rf][cf][r] + bv;
                if (BF16_OUT) ((u16*)Cout)[(size_t)row * ldc + col] = f2bf(v);
                else          ((float*)Cout)[(size_t)row * ldc + col] = v;
            }
        }
    }
}

// ---------------------------------------------------------------------------
// BN1 stats over implicit H1 = e*(P+Q)+b1.  PQ layout: [8192][512], P cols
// 0..255, Q cols 256..511.  e in {0,1}: e==0 rows contribute the constant b1
// (folded in closed form); the e-test is wave-uniform (no divergence).
// ---------------------------------------------------------------------------
__global__ __launch_bounds__(256) void stats1_kernel(
    const float* __restrict__ PQ, const float* __restrict__ edges,
    const float* __restrict__ b1, float* __restrict__ sums)
{
    __shared__ float Qs[NOBJ * HW];   // 32 KB
    __shared__ float es[NOBJ * NOBJ];
    const int b = blockIdx.x;
    const int t = threadIdx.x;

    const float* Qb = PQ + (size_t)b * (NOBJ * 512) + 256;
    for (int i = t; i < NOBJ * HW; i += 256) {
        const int r = i >> 8, c = i & 255;
        Qs[i] = Qb[r * 512 + c];
    }
    for (int i = t; i < NOBJ * NOBJ; i += 256)
        es[i] = edges[(size_t)b * (NOBJ * NOBJ) + i];
    __syncthreads();

    const float bk = b1[t];
    const float* Pb = PQ + (size_t)b * (NOBJ * 512);
    float s = 0.f, ss = 0.f;
    int n1 = 0;
    for (int i = 0; i < NOBJ; ++i) {
        const float p = Pb[i * 512 + t];
        const float* er = es + i * NOBJ;
        #pragma unroll
        for (int j = 0; j < NOBJ; ++j) {
            if (er[j] != 0.f) {
                const float x = p + Qs[j * HW + t] + bk;
                s += x;
                ss = fmaf(x, x, ss);
                ++n1;
            }
        }
    }
    const float n0 = (float)(NOBJ * NOBJ - n1);
    s += n0 * bk;
    ss = fmaf(n0, bk * bk, ss);
    atomicAdd(&sums[t], s);
    atomicAdd(&sums[HW + t], ss);
}

// ---------------------------------------------------------------------------
// S[b,i,k] = sum_j lrelu( e*(P+Q)*a + d ), finalize1 folded in, bf16 output.
// e==0 terms are the constant lrelu(d).
// ---------------------------------------------------------------------------
__global__ __launch_bounds__(256) void s_kernel(
    const float* __restrict__ PQ, const float* __restrict__ edges,
    const float* __restrict__ sums, const float* __restrict__ gamma,
    const float* __restrict__ beta, const float* __restrict__ b1,
    u16* __restrict__ Sb)
{
    __shared__ float Qs[NOBJ * HW];
    __shared__ float es[NOBJ * NOBJ];
    const int b = blockIdx.x;
    const int t = threadIdx.x;

    const float* Qb = PQ + (size_t)b * (NOBJ * 512) + 256;
    for (int i = t; i < NOBJ * HW; i += 256) {
        const int r = i >> 8, c = i & 255;
        Qs[i] = Qb[r * 512 + c];
    }
    for (int i = t; i < NOBJ * NOBJ; i += 256)
        es[i] = edges[(size_t)b * (NOBJ * NOBJ) + i];
    __syncthreads();

    const float invN = 1.f / (float)NPAIR;
    const float mean = sums[t] * invN;
    const float var  = fmaf(-mean, mean, sums[HW + t] * invN);
    const float a    = gamma[t] * rsqrtf(var + BN_EPS);
    const float d    = fmaf(b1[t] - mean, a, beta[t]);
    const float d0   = (d >= 0.f) ? d : 0.01f * d;

    const float* Pb = PQ + (size_t)b * (NOBJ * 512);
    for (int i = 0; i < NOBJ; ++i) {
        const float p = Pb[i * 512 + t];
        const float* er = es + i * NOBJ;
        float accv = 0.f;
        int n1 = 0;
        #pragma unroll
        for (int j = 0; j < NOBJ; ++j) {
            if (er[j] != 0.f) {
                const float x = fmaf(p + Qs[j * HW + t], a, d);
                accv += (x >= 0.f) ? x : 0.01f * x;
                ++n1;
            }
        }
        accv += (float)(NOBJ - n1) * d0;
        Sb[(size_t)b * (NOBJ * HW) + i * HW + t] = f2bf(accv);
    }
}

// ---------------------------------------------------------------------------
__global__ __launch_bounds__(256) void stats2_kernel(
    const float* __restrict__ H2, float* __restrict__ sums)
{
    const int t = threadIdx.x;
    const int blk = blockIdx.x;
    float s = 0.f, ss = 0.f;
    for (int r = 0; r < 128; ++r) {
        const float x = H2[(size_t)(blk * 128 + r) * HW + t];
        s += x;
        ss = fmaf(x, x, ss);
    }
    atomicAdd(&sums[t], s);
    atomicAdd(&sums[HW + t], ss);
}

// BN2 + leakyrelu + bf16 convert (finalize2 folded in per-thread).
__global__ __launch_bounds__(256) void act2b_kernel(
    const float* __restrict__ H2, const float* __restrict__ sums,
    const float* __restrict__ gamma, const float* __restrict__ beta,
    u16* __restrict__ H2b)
{
    const int idx = blockIdx.x * 256 + threadIdx.x;
    const int k = idx & (HW - 1);
    const float invN = 1.f / (float)R1;
    const float mean = sums[k] * invN;
    const float var  = fmaf(-mean, mean, sums[HW + k] * invN);
    const float a    = gamma[k] * rsqrtf(var + BN_EPS);
    const float d    = fmaf(-mean, a, beta[k]);
    float x = fmaf(H2[idx], a, d);
    x = (x >= 0.f) ? x : 0.01f * x;
    H2b[idx] = f2bf(x);
}

// ---------------------------------------------------------------------------
extern "C" void kernel_launch(void* const* d_in, const int* in_sizes, int n_in,
                              void* d_out, int out_size, void* d_ws, size_t ws_size,
                              hipStream_t stream)
{
    const float* state     = (const float*)d_in[0];
    const float* edges     = (const float*)d_in[1];
    const float* msg_w1    = (const float*)d_in[2];
    const float* msg_b1    = (const float*)d_in[3];
    const float* msg_gamma = (const float*)d_in[4];
    const float* msg_beta  = (const float*)d_in[5];
    const float* msg_w2    = (const float*)d_in[6];
    const float* msg_b2    = (const float*)d_in[7];
    const float* fin_w1    = (const float*)d_in[8];
    const float* fin_b1    = (const float*)d_in[9];
    const float* fin_gamma = (const float*)d_in[10];
    const float* fin_beta  = (const float*)d_in[11];
    const float* fin_w2    = (const float*)d_in[12];
    const float* fin_b2    = (const float*)d_in[13];

    char* w = (char*)d_ws;
    float* PQ   = (float*)(w);              // 8192x512 f32   (16 MB)
    float* H2   = (float*)(w + 16777216);   // 8192x256 f32   ( 8 MB)
    u16*   Ab   = (u16*)(w + 25165824);     // 8192x128 bf16  ( 2 MB)
    u16*   Sb   = (u16*)(w + 27262976);     // 8192x256 bf16  ( 4 MB)
    u16*   aggb = (u16*)(w + 31457280);     // 8192x128 bf16  ( 2 MB)
    u16*   H2b  = (u16*)(w + 33554432);     // 8192x256 bf16  ( 4 MB)
    u16*   W1b  = (u16*)(w + 37748736);     // 512x128 bf16
    u16*   W2b  = (u16*)(w + 37879808);     // 128x256 bf16
    u16*   FW1b = (u16*)(w + 37945344);     // 256x256 bf16
    u16*   FW2b = (u16*)(w + 38076416);     // 128x256 bf16
    float* sums = (float*)(w + 38141952);   // sums1 (512) + sums2 (512)

    hipMemsetAsync(sums, 0, 1024 * sizeof(float), stream);

    convert_kernel<<<1216, 256, 0, stream>>>(
        (const float4*)state, msg_w1, (const float4*)msg_w2,
        (const float4*)fin_w1, (const float4*)fin_w2,
        (u16x4*)Ab, (u16x4*)W1b, (u16x4*)W2b, (u16x4*)FW1b, (u16x4*)FW2b);

    // PQ = state_b @ [w1a|w1b]^T   (M=8192, N=512, K=128)
    mfma_gemm<2, 128, 128, false><<<dim3(8, 64), 256, 0, stream>>>(
        Ab, 128, nullptr, 0, W1b, nullptr, 0.f, PQ, 512);

    stats1_kernel<<<256, 256, 0, stream>>>(PQ, edges, msg_b1, sums);
    s_kernel<<<256, 256, 0, stream>>>(PQ, edges, sums, msg_gamma, msg_beta,
                                      msg_b1, Sb);

    // agg = S @ w2^T + 32*b2   (M=8192, N=128, K=256) -> bf16
    mfma_gemm<1, 256, 256, true><<<dim3(2, 128), 256, 0, stream>>>(
        Sb, 256, nullptr, 0, W2b, msg_b2, (float)NOBJ, aggb, 128);

    // H2 = [state_b | agg_b] @ fw1^T + fb1   (M=8192, N=256, K=256 split at 128)
    mfma_gemm<2, 256, 128, false><<<dim3(4, 64), 256, 0, stream>>>(
        Ab, 128, aggb, 128, FW1b, fin_b1, 1.f, H2, 256);

    stats2_kernel<<<64, 256, 0, stream>>>(H2, sums + 512);
    act2b_kernel<<<8192, 256, 0, stream>>>(H2, sums + 512, fin_gamma, fin_beta, H2b);

    // out = act(H2)_b @ fw2^T + fb2   (M=8192, N=128, K=256)
    mfma_gemm<1, 256, 256, false><<<dim3(2, 128), 256, 0, stream>>>(
        H2b, 256, nullptr, 0, FW2b, fin_b2, 1.f, (float*)d_out, 128);
}

// Round 3
// 104.070 us; speedup vs baseline: 1.9437x; 1.9437x over previous
//
#include <hip/hip_runtime.h>

#define NOBJ   32
#define DIM    128
#define HW     256
#define R1     8192
#define NPAIR  262144
#define BN_EPS 1e-5f

typedef unsigned short u16;
typedef unsigned int   u32;
typedef __attribute__((ext_vector_type(8))) short bf16x8;
typedef __attribute__((ext_vector_type(4))) float f32x4;
typedef __attribute__((ext_vector_type(4))) unsigned short u16x4;
typedef __attribute__((ext_vector_type(4))) unsigned int u32x4;

__device__ __forceinline__ u16 f2bf(float f) {
    union { float f; unsigned u; } v; v.f = f;
    unsigned r = v.u + 0x7fffu + ((v.u >> 16) & 1u);
    return (u16)(r >> 16);
}

__device__ __forceinline__ u16x4 cvt4(float4 v) {
    u16x4 r;
    r[0] = f2bf(v.x); r[1] = f2bf(v.y); r[2] = f2bf(v.z); r[3] = f2bf(v.w);
    return r;
}

// ---------------------------------------------------------------------------
// One-shot fp32 -> bf16 conversion of state + all weights.
// W1b remapped [512][128]: row n<256 = w1[n][0:128], row n>=256 = w1[n-256][128:256].
// ---------------------------------------------------------------------------
__global__ __launch_bounds__(256) void convert_kernel(
    const float4* __restrict__ state, const float* __restrict__ w1,
    const float4* __restrict__ w2, const float4* __restrict__ fw1,
    const float4* __restrict__ fw2,
    u16x4* __restrict__ Ab, u16x4* __restrict__ W1b, u16x4* __restrict__ W2b,
    u16x4* __restrict__ FW1b, u16x4* __restrict__ FW2b)
{
    int g = blockIdx.x * 256 + threadIdx.x;
    if (g < 262144) { Ab[g] = cvt4(state[g]); return; }
    g -= 262144;
    if (g < 16384) {
        const int o = g * 4, n = o >> 7, k = o & 127;
        const float4 v = *(const float4*)(w1 + (n < 256 ? n * 256 + k
                                                        : (n - 256) * 256 + 128 + k));
        W1b[g] = cvt4(v); return;
    }
    g -= 16384;
    if (g < 8192) { W2b[g] = cvt4(w2[g]); return; }
    g -= 8192;
    if (g < 16384) { FW1b[g] = cvt4(fw1[g]); return; }
    g -= 16384;
    if (g < 8192) { FW2b[g] = cvt4(fw2[g]); }
}

// ---------------------------------------------------------------------------
// bf16 MFMA GEMM, direct global->register. C = A @ W^T + bias_scale*bias.
// Wave tile 16*RF x 64; 4 waves stacked -> block BM = RF*64, BN = 64.
// k >= KSPLIT switches A-source to A2 (k rebased) for the implicit concat.
// ---------------------------------------------------------------------------
template<int RF, int K, int KSPLIT, bool BF16_OUT>
__global__ __launch_bounds__(256) void mfma_gemm(
    const u16* __restrict__ A, int lda,
    const u16* __restrict__ A2, int lda2,
    const u16* __restrict__ W,
    const float* __restrict__ bias, float bias_scale,
    void* __restrict__ Cout, int ldc)
{
    const int lane = threadIdx.x & 63;
    const int wave = threadIdx.x >> 6;
    const int row0 = blockIdx.y * (RF * 64) + wave * (RF * 16);
    const int col0 = blockIdx.x * 64;
    const int lr = lane & 15;
    const int lk = (lane >> 4) * 8;

    f32x4 acc[RF][4] = {};

    #pragma unroll
    for (int k0 = 0; k0 < K; k0 += 32) {
        const u16* Abase; int la;
        if (k0 < KSPLIT) { Abase = A + k0; la = lda; }
        else             { Abase = A2 + (k0 - KSPLIT); la = lda2; }
        bf16x8 afr[RF];
        #pragma unroll
        for (int rf = 0; rf < RF; ++rf)
            afr[rf] = *(const bf16x8*)(Abase + (size_t)(row0 + rf * 16 + lr) * la + lk);
        bf16x8 bfr[4];
        #pragma unroll
        for (int cf = 0; cf < 4; ++cf)
            bfr[cf] = *(const bf16x8*)(W + (size_t)(col0 + cf * 16 + lr) * K + k0 + lk);
        #pragma unroll
        for (int rf = 0; rf < RF; ++rf)
            #pragma unroll
            for (int cf = 0; cf < 4; ++cf)
                acc[rf][cf] = __builtin_amdgcn_mfma_f32_16x16x32_bf16(
                    afr[rf], bfr[cf], acc[rf][cf], 0, 0, 0);
    }

    #pragma unroll
    for (int rf = 0; rf < RF; ++rf) {
        #pragma unroll
        for (int cf = 0; cf < 4; ++cf) {
            const int col = col0 + cf * 16 + lr;
            const float bv = bias ? bias_scale * bias[col] : 0.f;
            #pragma unroll
            for (int r = 0; r < 4; ++r) {
                const int row = row0 + rf * 16 + (lane >> 4) * 4 + r;
                const float v = acc[rf][cf][r] + bv;
                if (BF16_OUT) ((u16*)Cout)[(size_t)row * ldc + col] = f2bf(v);
                else          ((float*)Cout)[(size_t)row * ldc + col] = v;
            }
        }
    }
}

// ---------------------------------------------------------------------------
// BN1 stats over implicit H1 = e*(P+Q)+b1, compacted edge lists.
// Grid (256 batches, 4 i-groups); block = 8 i rows, 256 threads, lane owns
// 4 columns (float4).  Pad entries hit zero row 32; corrected in closed form.
// ---------------------------------------------------------------------------
__global__ __launch_bounds__(256) void stats1_kernel(
    const float* __restrict__ PQ, const float* __restrict__ edges,
    const float* __restrict__ b1, float* __restrict__ sums)
{
    __shared__ float Qs[33 * 256];                       // 33 KB (row 32 = 0)
    __shared__ __align__(16) unsigned char list8[8 * 32];
    __shared__ int n1s[8];

    const int b    = blockIdx.x;
    const int i0   = blockIdx.y * 8;
    const int t    = threadIdx.x;
    const int lane = t & 63;
    const int w    = t >> 6;
    const int c0   = lane * 4;

    // stage raw Q rows (cols 256..511 of PQ) for this batch
    const float* Qb = PQ + (size_t)b * (32 * 512) + 256;
    f32x4* Qf4 = (f32x4*)Qs;
    #pragma unroll
    for (int it = 0; it < 8; ++it) {
        const int row = w + it * 4;
        Qf4[row * 64 + lane] = *(const f32x4*)(Qb + row * 512 + c0);
    }
    if (t < 64) Qf4[32 * 64 + t] = (f32x4){0.f, 0.f, 0.f, 0.f};
    if (t < 64) ((u32*)list8)[t] = 0x20202020u;          // pad sentinel j=32

    const int il_t = t >> 5;
    const int j_t  = t & 31;
    const float ev = edges[(size_t)b * 1024 + (i0 + il_t) * 32 + j_t];
    const bool val = (ev != 0.f);
    __syncthreads();

    const unsigned long long bal = __ballot(val);
    const u32 m32 = (lane < 32) ? (u32)bal : (u32)(bal >> 32);
    if (val) list8[il_t * 32 + __popc(m32 & ((1u << j_t) - 1u))] = (unsigned char)j_t;
    if (j_t == 0) n1s[il_t] = __popc(m32);
    __syncthreads();

    const f32x4 bk = *(const f32x4*)(b1 + c0);
    f32x4 s4 = {}, ss4 = {};

    #pragma unroll
    for (int ii = 0; ii < 2; ++ii) {
        const int il = 2 * w + ii;
        const int i  = i0 + il;
        const int n1   = n1s[il];
        const int npad = (n1 + 3) & ~3;
        const f32x4 p4 = *(const f32x4*)(PQ + (size_t)(b * 32 + i) * 512 + c0);
        f32x4 pb;
        #pragma unroll
        for (int k = 0; k < 4; ++k) pb[k] = p4[k] + bk[k];
        const float fz = (float)(32 - n1);     // e=0 count
        const float fp = (float)(npad - n1);   // pad count
        #pragma unroll
        for (int k = 0; k < 4; ++k) {
            s4[k]  += fz * bk[k] - fp * pb[k];
            ss4[k] += fz * bk[k] * bk[k] - fp * pb[k] * pb[k];
        }
        const u32x4 l0 = *(const u32x4*)(list8 + il * 32);
        const u32x4 l1 = *(const u32x4*)(list8 + il * 32 + 16);
        const u32 wbuf[8] = {l0[0], l0[1], l0[2], l0[3], l1[0], l1[1], l1[2], l1[3]};
        #pragma unroll
        for (int wi = 0; wi < 8; ++wi) {
            if (wi * 4 >= npad) break;
            const u32 w4 = wbuf[wi];
            #pragma unroll
            for (int kb = 0; kb < 4; ++kb) {
                const int j = (w4 >> (kb * 8)) & 0xff;
                const f32x4 q = Qf4[j * 64 + lane];
                #pragma unroll
                for (int k = 0; k < 4; ++k) {
                    const float x = pb[k] + q[k];
                    s4[k] += x;
                    ss4[k] = fmaf(x, x, ss4[k]);
                }
            }
        }
    }

    __syncthreads();                      // everyone done reading Qs
    *(f32x4*)(Qs + w * 256 + c0)        = s4;   // reuse Qs as reduction buffer
    *(f32x4*)(Qs + 1024 + w * 256 + c0) = ss4;
    __syncthreads();
    float as = 0.f, ass = 0.f;
    #pragma unroll
    for (int ww = 0; ww < 4; ++ww) {
        as  += Qs[ww * 256 + t];
        ass += Qs[1024 + ww * 256 + t];
    }
    atomicAdd(&sums[t], as);
    atomicAdd(&sums[256 + t], ass);
}

// ---------------------------------------------------------------------------
// S[b,i,:] = sum_j lrelu(a*(P+Q)+d) with finalize1 folded; bf16 out.
// Same structure as stats1; Q staged pre-scaled by a.
// ---------------------------------------------------------------------------
__global__ __launch_bounds__(256) void s_kernel(
    const float* __restrict__ PQ, const float* __restrict__ edges,
    const float* __restrict__ sums, const float* __restrict__ gamma,
    const float* __restrict__ beta, const float* __restrict__ b1,
    u16* __restrict__ Sb)
{
    __shared__ float Qs[33 * 256];
    __shared__ __align__(16) unsigned char list8[8 * 32];
    __shared__ int n1s[8];

    const int b    = blockIdx.x;
    const int i0   = blockIdx.y * 8;
    const int t    = threadIdx.x;
    const int lane = t & 63;
    const int w    = t >> 6;
    const int c0   = lane * 4;

    // BN coefficients for my 4 columns
    const float invN = 1.f / (float)NPAIR;
    const f32x4 s1  = *(const f32x4*)(sums + c0);
    const f32x4 s2  = *(const f32x4*)(sums + 256 + c0);
    const f32x4 g4  = *(const f32x4*)(gamma + c0);
    const f32x4 be4 = *(const f32x4*)(beta + c0);
    const f32x4 b14 = *(const f32x4*)(b1 + c0);
    f32x4 a4, d4, ld4;
    #pragma unroll
    for (int k = 0; k < 4; ++k) {
        const float mean = s1[k] * invN;
        const float var  = fmaf(-mean, mean, s2[k] * invN);
        a4[k]  = g4[k] * rsqrtf(var + BN_EPS);
        d4[k]  = fmaf(b14[k] - mean, a4[k], be4[k]);
        ld4[k] = fmaxf(d4[k], 0.01f * d4[k]);
    }

    // stage a-scaled Q rows
    const float* Qb = PQ + (size_t)b * (32 * 512) + 256;
    f32x4* Qf4 = (f32x4*)Qs;
    #pragma unroll
    for (int it = 0; it < 8; ++it) {
        const int row = w + it * 4;
        f32x4 q = *(const f32x4*)(Qb + row * 512 + c0);
        #pragma unroll
        for (int k = 0; k < 4; ++k) q[k] *= a4[k];
        Qf4[row * 64 + lane] = q;
    }
    if (t < 64) Qf4[32 * 64 + t] = (f32x4){0.f, 0.f, 0.f, 0.f};
    if (t < 64) ((u32*)list8)[t] = 0x20202020u;

    const int il_t = t >> 5;
    const int j_t  = t & 31;
    const float ev = edges[(size_t)b * 1024 + (i0 + il_t) * 32 + j_t];
    const bool val = (ev != 0.f);
    __syncthreads();

    const unsigned long long bal = __ballot(val);
    const u32 m32 = (lane < 32) ? (u32)bal : (u32)(bal >> 32);
    if (val) list8[il_t * 32 + __popc(m32 & ((1u << j_t) - 1u))] = (unsigned char)j_t;
    if (j_t == 0) n1s[il_t] = __popc(m32);
    __syncthreads();

    #pragma unroll
    for (int ii = 0; ii < 2; ++ii) {
        const int il = 2 * w + ii;
        const int i  = i0 + il;
        const int n1   = n1s[il];
        const int npad = (n1 + 3) & ~3;
        const f32x4 p4 = *(const f32x4*)(PQ + (size_t)(b * 32 + i) * 512 + c0);
        f32x4 ap, acc;
        const float fz = (float)(32 - n1);
        const float fp = (float)(npad - n1);
        #pragma unroll
        for (int k = 0; k < 4; ++k) {
            ap[k] = fmaf(a4[k], p4[k], d4[k]);
            const float lap = fmaxf(ap[k], 0.01f * ap[k]);
            acc[k] = fz * ld4[k] - fp * lap;
        }
        const u32x4 l0 = *(const u32x4*)(list8 + il * 32);
        const u32x4 l1 = *(const u32x4*)(list8 + il * 32 + 16);
        const u32 wbuf[8] = {l0[0], l0[1], l0[2], l0[3], l1[0], l1[1], l1[2], l1[3]};
        #pragma unroll
        for (int wi = 0; wi < 8; ++wi) {
            if (wi * 4 >= npad) break;
            const u32 w4 = wbuf[wi];
            #pragma unroll
            for (int kb = 0; kb < 4; ++kb) {
                const int j = (w4 >> (kb * 8)) & 0xff;
                const f32x4 q = Qf4[j * 64 + lane];
                #pragma unroll
                for (int k = 0; k < 4; ++k) {
                    const float x = ap[k] + q[k];
                    acc[k] += fmaxf(x, 0.01f * x);
                }
            }
        }
        u16x4 o;
        #pragma unroll
        for (int k = 0; k < 4; ++k) o[k] = f2bf(acc[k]);
        *(u16x4*)(Sb + (size_t)(b * 32 + i) * 256 + c0) = o;
    }
}

// ---------------------------------------------------------------------------
__global__ __launch_bounds__(256) void stats2_kernel(
    const float* __restrict__ H2, float* __restrict__ sums)
{
    const int t = threadIdx.x;
    const int r0 = blockIdx.x * 16;
    float s = 0.f, ss = 0.f;
    for (int r = 0; r < 16; ++r) {
        const float x = H2[(size_t)(r0 + r) * HW + t];
        s += x;
        ss = fmaf(x, x, ss);
    }
    atomicAdd(&sums[t], s);
    atomicAdd(&sums[HW + t], ss);
}

// BN2 + leakyrelu + bf16 convert.
__global__ __launch_bounds__(256) void act2b_kernel(
    const float* __restrict__ H2, const float* __restrict__ sums,
    const float* __restrict__ gamma, const float* __restrict__ beta,
    u16* __restrict__ H2b)
{
    const int idx = blockIdx.x * 256 + threadIdx.x;
    const int k = idx & (HW - 1);
    const float invN = 1.f / (float)R1;
    const float mean = sums[k] * invN;
    const float var  = fmaf(-mean, mean, sums[HW + k] * invN);
    const float a    = gamma[k] * rsqrtf(var + BN_EPS);
    const float d    = fmaf(-mean, a, beta[k]);
    float x = fmaf(H2[idx], a, d);
    x = (x >= 0.f) ? x : 0.01f * x;
    H2b[idx] = f2bf(x);
}

// ---------------------------------------------------------------------------
extern "C" void kernel_launch(void* const* d_in, const int* in_sizes, int n_in,
                              void* d_out, int out_size, void* d_ws, size_t ws_size,
                              hipStream_t stream)
{
    const float* state     = (const float*)d_in[0];
    const float* edges     = (const float*)d_in[1];
    const float* msg_w1    = (const float*)d_in[2];
    const float* msg_b1    = (const float*)d_in[3];
    const float* msg_gamma = (const float*)d_in[4];
    const float* msg_beta  = (const float*)d_in[5];
    const float* msg_w2    = (const float*)d_in[6];
    const float* msg_b2    = (const float*)d_in[7];
    const float* fin_w1    = (const float*)d_in[8];
    const float* fin_b1    = (const float*)d_in[9];
    const float* fin_gamma = (const float*)d_in[10];
    const float* fin_beta  = (const float*)d_in[11];
    const float* fin_w2    = (const float*)d_in[12];
    const float* fin_b2    = (const float*)d_in[13];

    char* w = (char*)d_ws;
    float* PQ   = (float*)(w);              // 8192x512 f32   (16 MB)
    float* H2   = (float*)(w + 16777216);   // 8192x256 f32   ( 8 MB)
    u16*   Ab   = (u16*)(w + 25165824);     // 8192x128 bf16  ( 2 MB)
    u16*   Sb   = (u16*)(w + 27262976);     // 8192x256 bf16  ( 4 MB)
    u16*   aggb = (u16*)(w + 31457280);     // 8192x128 bf16  ( 2 MB)
    u16*   H2b  = (u16*)(w + 33554432);     // 8192x256 bf16  ( 4 MB)
    u16*   W1b  = (u16*)(w + 37748736);
    u16*   W2b  = (u16*)(w + 37879808);
    u16*   FW1b = (u16*)(w + 37945344);
    u16*   FW2b = (u16*)(w + 38076416);
    float* sums = (float*)(w + 38141952);   // sums1 (512) + sums2 (512)

    hipMemsetAsync(sums, 0, 1024 * sizeof(float), stream);

    convert_kernel<<<1216, 256, 0, stream>>>(
        (const float4*)state, msg_w1, (const float4*)msg_w2,
        (const float4*)fin_w1, (const float4*)fin_w2,
        (u16x4*)Ab, (u16x4*)W1b, (u16x4*)W2b, (u16x4*)FW1b, (u16x4*)FW2b);

    // PQ = state_b @ [w1a|w1b]^T   (M=8192, N=512, K=128)
    mfma_gemm<2, 128, 128, false><<<dim3(8, 64), 256, 0, stream>>>(
        Ab, 128, nullptr, 0, W1b, nullptr, 0.f, PQ, 512);

    stats1_kernel<<<dim3(256, 4), 256, 0, stream>>>(PQ, edges, msg_b1, sums);
    s_kernel<<<dim3(256, 4), 256, 0, stream>>>(PQ, edges, sums, msg_gamma,
                                               msg_beta, msg_b1, Sb);

    // agg = S @ w2^T + 32*b2   (M=8192, N=128, K=256) -> bf16
    mfma_gemm<1, 256, 256, true><<<dim3(2, 128), 256, 0, stream>>>(
        Sb, 256, nullptr, 0, W2b, msg_b2, (float)NOBJ, aggb, 128);

    // H2 = [state_b | agg_b] @ fw1^T + fb1   (M=8192, N=256, K split at 128)
    mfma_gemm<2, 256, 128, false><<<dim3(4, 64), 256, 0, stream>>>(
        Ab, 128, aggb, 128, FW1b, fin_b1, 1.f, H2, 256);

    stats2_kernel<<<512, 256, 0, stream>>>(H2, sums + 512);
    act2b_kernel<<<8192, 256, 0, stream>>>(H2, sums + 512, fin_gamma, fin_beta, H2b);

    // out = act(H2)_b @ fw2^T + fb2   (M=8192, N=128, K=256)
    mfma_gemm<1, 256, 256, false><<<dim3(2, 128), 256, 0, stream>>>(
        H2b, 256, nullptr, 0, FW2b, fin_b2, 1.f, (float*)d_out, 128);
}